// Round 1
// baseline (49.989 us; speedup 1.0000x reference)
//
#include <hip/hip_runtime.h>

namespace {
constexpr int Cc   = 32;
constexpr int H    = 128;
constexpr int W    = 128;
constexpr int HWsz = H * W;        // 16384
constexpr int NPIX = 8 * HWsz;     // 131072
constexpr int NBLK = NPIX / 256;   // 512
}

__global__ __launch_bounds__(256) void cl_bnorm_kernel(const float* __restrict__ B,
                                                       float* __restrict__ rnB) {
    int p  = blockIdx.x * 256 + threadIdx.x;      // pixel id 0..131071
    int b  = p >> 14;
    int hw = p & (HWsz - 1);
    const float* Bp = B + (size_t)b * Cc * HWsz + hw;
    float s = 0.f;
#pragma unroll
    for (int c = 0; c < Cc; ++c) {
        float x = Bp[c * HWsz];
        s += x * x;
    }
    rnB[p] = 1.0f / fmaxf(sqrtf(s), 1e-12f);
}

__global__ __launch_bounds__(256) void cl_loss_kernel(const float* __restrict__ A,
                                                      const float* __restrict__ B,
                                                      const float* __restrict__ rnB,
                                                      double* __restrict__ partial) {
    int p  = blockIdx.x * 256 + threadIdx.x;
    int w  = p & (W - 1);
    int h  = (p >> 7) & (H - 1);
    int b  = p >> 14;
    int hw = p & (HWsz - 1);
    int bbase = p & ~(HWsz - 1);                  // b * HWsz

    const float* Ap = A + (size_t)b * Cc * HWsz + hw;
    const float* Bb = B + (size_t)b * Cc * HWsz;

    float sim[9];
    int   off[9];
    bool  valid[9];
#pragma unroll
    for (int k = 0; k < 9; ++k) {
        int di = k / 3 - 1, dj = k % 3 - 1;
        int hh = h + di, ww = w + dj;
        bool v = ((unsigned)hh < (unsigned)H) && ((unsigned)ww < (unsigned)W);
        valid[k] = v;
        off[k]   = v ? hh * W + ww : hw;          // safe addr for invalid
        sim[k]   = 0.f;
    }

    float sa = 0.f;
    for (int c = 0; c < Cc; ++c) {
        float a = Ap[c * HWsz];
        sa += a * a;
        const float* Bc = Bb + c * HWsz;
#pragma unroll
        for (int k = 0; k < 9; ++k) sim[k] += a * Bc[off[k]];
    }
    float ra = 1.0f / fmaxf(sqrtf(sa), 1e-12f);

    float logits[9];
    float m = -1e30f;
#pragma unroll
    for (int k = 0; k < 9; ++k) {
        float s = valid[k] ? sim[k] * ra * rnB[bbase + off[k]] : 0.0f;
        sim[k]    = s;
        float l   = s / 0.07f;                    // match reference: divide, fp32
        logits[k] = l;
        m = fmaxf(m, l);
    }
    float Z = 0.f;
#pragma unroll
    for (int k = 0; k < 9; ++k) Z += expf(logits[k] - m);
    float lZ = logf(Z);

    float acc = 0.f;
#pragma unroll
    for (int k = 0; k < 9; ++k) {
        if (sim[k] > 0.5f) acc += (m + lZ - logits[k]);   // -log_prob
    }

    __shared__ double sd[256];
    sd[threadIdx.x] = (double)acc;
    __syncthreads();
    for (int s = 128; s > 0; s >>= 1) {
        if (threadIdx.x < s) sd[threadIdx.x] += sd[threadIdx.x + s];
        __syncthreads();
    }
    if (threadIdx.x == 0) partial[blockIdx.x] = sd[0];
}

__global__ __launch_bounds__(256) void cl_final_kernel(const double* __restrict__ partial,
                                                       float* __restrict__ out) {
    __shared__ double sd[256];
    double acc = 0.0;
    for (int i = threadIdx.x; i < NBLK; i += 256) acc += partial[i];
    sd[threadIdx.x] = acc;
    __syncthreads();
    for (int s = 128; s > 0; s >>= 1) {
        if (threadIdx.x < s) sd[threadIdx.x] += sd[threadIdx.x + s];
        __syncthreads();
    }
    if (threadIdx.x == 0) out[0] = (float)(sd[0] / (double)NPIX);
}

extern "C" void kernel_launch(void* const* d_in, const int* in_sizes, int n_in,
                              void* d_out, int out_size, void* d_ws, size_t ws_size,
                              hipStream_t stream) {
    const float* A = (const float*)d_in[0];
    const float* B = (const float*)d_in[1];
    float* out = (float*)d_out;

    char* ws = (char*)d_ws;
    float*  rnB     = (float*)ws;                          // 131072 * 4 = 512 KiB
    double* partial = (double*)(ws + (size_t)NPIX * 4);    // 512 * 8   =   4 KiB

    cl_bnorm_kernel<<<NBLK, 256, 0, stream>>>(B, rnB);
    cl_loss_kernel<<<NBLK, 256, 0, stream>>>(A, B, rnB, partial);
    cl_final_kernel<<<1, 256, 0, stream>>>(partial, out);
}

// Round 2
// 29.730 us; speedup vs baseline: 1.6815x; 1.6815x over previous
//
#include <hip/hip_runtime.h>

namespace {
constexpr int Cc     = 32;
constexpr int H      = 128;
constexpr int W      = 128;
constexpr int HWsz   = H * W;          // 16384
constexpr int NPIX   = 8 * HWsz;       // 131072
constexpr int GROUPS = 4;              // channel groups per pixel
constexpr int CPG    = Cc / GROUPS;    // 8 channels per group
constexpr int PPB    = 64;             // pixels per block (one wave)
constexpr int NBLK   = NPIX / PPB;     // 2048 blocks
}

// rnB: per-pixel 1/max(||B||,eps). Channel-split across 4 groups for TLP.
__global__ __launch_bounds__(256) void cl_bnorm_kernel(const float* __restrict__ B,
                                                       float* __restrict__ rnB) {
    int lane = threadIdx.x & 63;
    int g    = threadIdx.x >> 6;
    int p    = blockIdx.x * PPB + lane;
    int b    = p >> 14;
    int hw   = p & (HWsz - 1);
    const float* Bp = B + (size_t)b * Cc * HWsz + (size_t)g * CPG * HWsz + hw;
    float s = 0.f;
#pragma unroll
    for (int c = 0; c < CPG; ++c) {
        float x = Bp[c * HWsz];
        s += x * x;
    }
    __shared__ float sd[256];
    sd[threadIdx.x] = s;
    __syncthreads();
    if (g == 0) {
        float t = sd[lane] + sd[64 + lane] + sd[128 + lane] + sd[192 + lane];
        rnB[p] = 1.0f / fmaxf(sqrtf(t), 1e-12f);
    }
}

__global__ __launch_bounds__(256) void cl_loss_kernel(const float* __restrict__ A,
                                                      const float* __restrict__ B,
                                                      const float* __restrict__ rnB,
                                                      double* __restrict__ partial) {
    int lane = threadIdx.x & 63;
    int g    = threadIdx.x >> 6;
    int p    = blockIdx.x * PPB + lane;
    int w    = p & (W - 1);
    int h    = (p >> 7) & (H - 1);
    int b    = p >> 14;
    int hw   = p & (HWsz - 1);
    int bbase = p & ~(HWsz - 1);       // b * HWsz

    const float* Ap = A + (size_t)b * Cc * HWsz + (size_t)g * CPG * HWsz + hw;
    const float* Bb = B + (size_t)b * Cc * HWsz + (size_t)g * CPG * HWsz;

    float sim[9];
    int   off[9];
    bool  valid[9];
#pragma unroll
    for (int k = 0; k < 9; ++k) {
        int di = k / 3 - 1, dj = k % 3 - 1;
        int hh = h + di, ww = w + dj;
        bool v = ((unsigned)hh < (unsigned)H) && ((unsigned)ww < (unsigned)W);
        valid[k] = v;
        off[k]   = v ? hh * W + ww : hw;
        sim[k]   = 0.f;
    }

    float sa = 0.f;
#pragma unroll
    for (int c = 0; c < CPG; ++c) {
        float a = Ap[c * HWsz];
        sa += a * a;
        const float* Bc = Bb + c * HWsz;
#pragma unroll
        for (int k = 0; k < 9; ++k) sim[k] += a * Bc[off[k]];
    }

    // Cross-group reduce: groups 1..3 park partials in LDS; group 0 adds.
    __shared__ float lsim[192 * 9];    // 6912 floats = 27 KiB
    __shared__ float lsa[192];
    if (g != 0) {
        int t = threadIdx.x - 64;
#pragma unroll
        for (int k = 0; k < 9; ++k) lsim[t * 9 + k] = sim[k];
        lsa[t] = sa;
    }
    __syncthreads();

    if (g == 0) {
#pragma unroll
        for (int k = 0; k < 9; ++k)
            sim[k] += lsim[lane * 9 + k] + lsim[(64 + lane) * 9 + k] + lsim[(128 + lane) * 9 + k];
        sa += lsa[lane] + lsa[64 + lane] + lsa[128 + lane];
        float ra = 1.0f / fmaxf(sqrtf(sa), 1e-12f);

        float logits[9];
        float m = -1e30f;
#pragma unroll
        for (int k = 0; k < 9; ++k) {
            float s = valid[k] ? sim[k] * ra * rnB[bbase + off[k]] : 0.0f;
            sim[k]    = s;
            float l   = s / 0.07f;
            logits[k] = l;
            m = fmaxf(m, l);
        }
        float Z = 0.f;
#pragma unroll
        for (int k = 0; k < 9; ++k) Z += expf(logits[k] - m);
        float lZ = logf(Z);

        float accf = 0.f;
#pragma unroll
        for (int k = 0; k < 9; ++k) {
            if (sim[k] > 0.5f) accf += (m + lZ - logits[k]);
        }

        // in-wave reduce (all 64 values live in wave 0)
        double acc = (double)accf;
#pragma unroll
        for (int s = 32; s > 0; s >>= 1) acc += __shfl_down(acc, s, 64);
        if (lane == 0) partial[blockIdx.x] = acc;
    }
}

__global__ __launch_bounds__(256) void cl_final_kernel(const double* __restrict__ partial,
                                                       float* __restrict__ out) {
    __shared__ double sd[256];
    double acc = 0.0;
    for (int i = threadIdx.x; i < NBLK; i += 256) acc += partial[i];
    sd[threadIdx.x] = acc;
    __syncthreads();
    for (int s = 128; s > 0; s >>= 1) {
        if (threadIdx.x < s) sd[threadIdx.x] += sd[threadIdx.x + s];
        __syncthreads();
    }
    if (threadIdx.x == 0) out[0] = (float)(sd[0] / (double)NPIX);
}

extern "C" void kernel_launch(void* const* d_in, const int* in_sizes, int n_in,
                              void* d_out, int out_size, void* d_ws, size_t ws_size,
                              hipStream_t stream) {
    const float* A = (const float*)d_in[0];
    const float* B = (const float*)d_in[1];
    float* out = (float*)d_out;

    char* ws = (char*)d_ws;
    float*  rnB     = (float*)ws;                          // 131072 * 4 = 512 KiB
    double* partial = (double*)(ws + (size_t)NPIX * 4);    // 2048 * 8  =  16 KiB

    cl_bnorm_kernel<<<NBLK, 256, 0, stream>>>(B, rnB);
    cl_loss_kernel<<<NBLK, 256, 0, stream>>>(A, B, rnB, partial);
    cl_final_kernel<<<1, 256, 0, stream>>>(partial, out);
}

// Round 3
// 24.337 us; speedup vs baseline: 2.0541x; 1.2216x over previous
//
#include <hip/hip_runtime.h>

namespace {
constexpr int Cc   = 32;
constexpr int H    = 128;
constexpr int W    = 128;
constexpr int HWsz = H * W;          // 16384
constexpr int NPIX = 8 * HWsz;       // 131072
constexpr int PPB  = 256;            // pixels per block (2 rows of 128)
constexpr int NBLK = NPIX / PPB;     // 512
constexpr int CPG  = 8;              // channels per group (4 groups = 4 waves)
}

// compile-time component get (j must be a literal after unroll)
#define CGET(v, j) ((j) == 0 ? (v).x : ((j) == 1 ? (v).y : ((j) == 2 ? (v).z : (v).w)))

__device__ inline float4 mk4(float a, float b, float c, float d) {
    float4 r; r.x = a; r.y = b; r.z = c; r.w = d; return r;
}
__device__ inline void fma4(float4& acc, const float4& a, const float4& b) {
    acc.x += a.x * b.x; acc.y += a.y * b.y; acc.z += a.z * b.z; acc.w += a.w * b.w;
}
__device__ inline void add4(float4& acc, const float4& v) {
    acc.x += v.x; acc.y += v.y; acc.z += v.z; acc.w += v.w;
}

// rnB[p] = 1 / max(||B[:,p]||, eps), 4 pixels/thread, 4 channel-groups.
__global__ __launch_bounds__(256) void cl_bnorm_kernel(const float* __restrict__ B,
                                                       float* __restrict__ rnB) {
    int t  = threadIdx.x & 63;
    int g  = threadIdx.x >> 6;
    int p0 = blockIdx.x * PPB + t * 4;
    int b  = p0 >> 14;
    int hw = p0 & (HWsz - 1);
    const float* Bp = B + (size_t)b * Cc * HWsz + (size_t)g * CPG * HWsz + hw;
    float4 s = mk4(0, 0, 0, 0);
#pragma unroll
    for (int c = 0; c < CPG; ++c) {
        float4 x = *(const float4*)(Bp + c * HWsz);
        fma4(s, x, x);
    }
    __shared__ float4 ls[192];
    if (g != 0) ls[(g - 1) * 64 + t] = s;
    __syncthreads();
    if (g == 0) {
        add4(s, ls[t]); add4(s, ls[64 + t]); add4(s, ls[128 + t]);
        float4 r;
        r.x = 1.0f / fmaxf(sqrtf(s.x), 1e-12f);
        r.y = 1.0f / fmaxf(sqrtf(s.y), 1e-12f);
        r.z = 1.0f / fmaxf(sqrtf(s.z), 1e-12f);
        r.w = 1.0f / fmaxf(sqrtf(s.w), 1e-12f);
        *(float4*)(rnB + p0) = r;
    }
}

__global__ __launch_bounds__(256) void cl_loss_kernel(const float* __restrict__ A,
                                                      const float* __restrict__ B,
                                                      const float* __restrict__ rnB,
                                                      double* __restrict__ partial) {
    int t  = threadIdx.x & 63;        // quad id in block; also lane (group==wave)
    int g  = threadIdx.x >> 6;        // channel group == wave id
    int p0 = blockIdx.x * PPB + t * 4;
    int b  = p0 >> 14;
    int hw = p0 & (HWsz - 1);
    int h  = hw >> 7;
    int w0 = hw & (W - 1);            // multiple of 4

    const float* Ap = A + (size_t)b * Cc * HWsz + (size_t)g * CPG * HWsz + hw;
    int hc[3];
#pragma unroll
    for (int r = 0; r < 3; ++r) hc[r] = min(max(h + r - 1, 0), H - 1);
    const float* Bg  = B + (size_t)b * Cc * HWsz + (size_t)g * CPG * HWsz;
    const float* Br0 = Bg + hc[0] * W + w0;
    const float* Br1 = Bg + hc[1] * W + w0;
    const float* Br2 = Bg + hc[2] * W + w0;

    float4 sim[9];
#pragma unroll
    for (int k = 0; k < 9; ++k) sim[k] = mk4(0, 0, 0, 0);
    float4 sa4 = mk4(0, 0, 0, 0);

#pragma unroll
    for (int c = 0; c < CPG; ++c) {
        float4 a4 = *(const float4*)(Ap  + c * HWsz);
        float4 b0 = *(const float4*)(Br0 + c * HWsz);
        float4 b1 = *(const float4*)(Br1 + c * HWsz);
        float4 b2 = *(const float4*)(Br2 + c * HWsz);
        float l0 = __shfl_up(b0.w, 1, 64), r0 = __shfl_down(b0.x, 1, 64);
        float l1 = __shfl_up(b1.w, 1, 64), r1 = __shfl_down(b1.x, 1, 64);
        float l2 = __shfl_up(b2.w, 1, 64), r2 = __shfl_down(b2.x, 1, 64);
        fma4(sa4, a4, a4);
        fma4(sim[0], a4, mk4(l0, b0.x, b0.y, b0.z));
        fma4(sim[1], a4, b0);
        fma4(sim[2], a4, mk4(b0.y, b0.z, b0.w, r0));
        fma4(sim[3], a4, mk4(l1, b1.x, b1.y, b1.z));
        fma4(sim[4], a4, b1);
        fma4(sim[5], a4, mk4(b1.y, b1.z, b1.w, r1));
        fma4(sim[6], a4, mk4(l2, b2.x, b2.y, b2.z));
        fma4(sim[7], a4, b2);
        fma4(sim[8], a4, mk4(b2.y, b2.z, b2.w, r2));
    }

    // cross-group reduce: stride 36 floats -> b128 bank-quads 2-way (free)
    __shared__ float  lsim[3 * 64 * 36];    // 27 KiB
    __shared__ float4 lsa[192];             //  3 KiB
    if (g != 0) {
        float* dst = &lsim[((g - 1) * 64 + t) * 36];
#pragma unroll
        for (int k = 0; k < 9; ++k) *(float4*)(dst + k * 4) = sim[k];
        lsa[(g - 1) * 64 + t] = sa4;
    }
    __syncthreads();

    if (g == 0) {
#pragma unroll
        for (int gg = 0; gg < 3; ++gg) {
            const float* src = &lsim[(gg * 64 + t) * 36];
#pragma unroll
            for (int k = 0; k < 9; ++k) add4(sim[k], *(const float4*)(src + k * 4));
            add4(sa4, lsa[gg * 64 + t]);
        }

        // neighbor 1/||B|| rows
        const float* Rb = rnB + (size_t)b * HWsz;
        float4 rb[3]; float rlf[3], rrt[3];
#pragma unroll
        for (int r = 0; r < 3; ++r) {
            rb[r]  = *(const float4*)(Rb + hc[r] * W + w0);
            rlf[r] = __shfl_up(rb[r].w, 1, 64);
            rrt[r] = __shfl_down(rb[r].x, 1, 64);
        }

        float accf = 0.f;
#pragma unroll
        for (int j = 0; j < 4; ++j) {
            float ra = 1.0f / fmaxf(sqrtf(CGET(sa4, j)), 1e-12f);
            float lg[9], sv[9];
#pragma unroll
            for (int r = 0; r < 3; ++r) {
                bool vr_ = ((unsigned)(h + r - 1) < (unsigned)H);
                float nl = (j == 0) ? rlf[r] : CGET(rb[r], (j > 0 ? j - 1 : 0));
                float nm = CGET(rb[r], j);
                float nr = (j == 3) ? rrt[r] : CGET(rb[r], (j < 3 ? j + 1 : 3));
                bool vl  = vr_ && (j > 0 || w0 > 0);
                bool vrg = vr_ && (j < 3 || w0 < W - 4);
                float s0 = vl  ? CGET(sim[r * 3 + 0], j) * ra * nl : 0.f;
                float s1 = vr_ ? CGET(sim[r * 3 + 1], j) * ra * nm : 0.f;
                float s2 = vrg ? CGET(sim[r * 3 + 2], j) * ra * nr : 0.f;
                sv[r * 3 + 0] = s0; lg[r * 3 + 0] = s0 / 0.07f;
                sv[r * 3 + 1] = s1; lg[r * 3 + 1] = s1 / 0.07f;
                sv[r * 3 + 2] = s2; lg[r * 3 + 2] = s2 / 0.07f;
            }
            float m = -1e30f;
#pragma unroll
            for (int k = 0; k < 9; ++k) m = fmaxf(m, lg[k]);
            float Z = 0.f;
#pragma unroll
            for (int k = 0; k < 9; ++k) Z += expf(lg[k] - m);
            float lZ = logf(Z);
#pragma unroll
            for (int k = 0; k < 9; ++k)
                if (sv[k] > 0.5f) accf += (m + lZ - lg[k]);
        }

        double acc = (double)accf;
#pragma unroll
        for (int s = 32; s > 0; s >>= 1) acc += __shfl_down(acc, s, 64);
        if (t == 0) partial[blockIdx.x] = acc;
    }
}

__global__ __launch_bounds__(256) void cl_final_kernel(const double* __restrict__ partial,
                                                       float* __restrict__ out) {
    __shared__ double sd[256];
    double acc = 0.0;
    for (int i = threadIdx.x; i < NBLK; i += 256) acc += partial[i];
    sd[threadIdx.x] = acc;
    __syncthreads();
    for (int s = 128; s > 0; s >>= 1) {
        if (threadIdx.x < s) sd[threadIdx.x] += sd[threadIdx.x + s];
        __syncthreads();
    }
    if (threadIdx.x == 0) out[0] = (float)(sd[0] / (double)NPIX);
}

extern "C" void kernel_launch(void* const* d_in, const int* in_sizes, int n_in,
                              void* d_out, int out_size, void* d_ws, size_t ws_size,
                              hipStream_t stream) {
    const float* A = (const float*)d_in[0];
    const float* B = (const float*)d_in[1];
    float* out = (float*)d_out;

    char* ws = (char*)d_ws;
    float*  rnB     = (float*)ws;                          // 512 KiB
    double* partial = (double*)(ws + (size_t)NPIX * 4);    // 4 KiB

    cl_bnorm_kernel<<<NBLK, 256, 0, stream>>>(B, rnB);
    cl_loss_kernel<<<NBLK, 256, 0, stream>>>(A, B, rnB, partial);
    cl_final_kernel<<<1, 256, 0, stream>>>(partial, out);
}